// Round 9
// baseline (1021.467 us; speedup 1.0000x reference)
//
#include <hip/hip_runtime.h>

typedef _Float16 half8 __attribute__((ext_vector_type(8)));
typedef _Float16 half4 __attribute__((ext_vector_type(4)));
typedef float floatx4 __attribute__((ext_vector_type(4)));

template<int N> struct ic { static constexpr int value = N; };

__device__ __forceinline__ float fast_rcp(float x) { return __builtin_amdgcn_rcpf(x); }
__device__ __forceinline__ float fast_sigmoid(float x) { return fast_rcp(1.f + __expf(-x)); }
__device__ __forceinline__ float fast_tanh(float x) { return 1.f - 2.f*fast_rcp(1.f + __expf(2.f*x)); }

// ---------------- prep: fp16 fragment-ordered weights + bias sums + prog zero ----
// B-frag layout for mfma_f32_16x16x32_f16: lane L, reg j holds
// W[n = ntile*16 + (L&15)][k = ktile*32 + (L>>4)*8 + j].
// Buffer: [ktile][ntile(32)][lane(64)][8 f16]. Verified correct across all rounds.
__global__ void prep_kernel(const float* __restrict__ wih0, const float* __restrict__ whh0,
                            const float* __restrict__ bih0, const float* __restrict__ bhh0,
                            const float* __restrict__ wih1, const float* __restrict__ whh1,
                            const float* __restrict__ bih1, const float* __restrict__ bhh1,
                            _Float16* __restrict__ w0f, _Float16* __restrict__ w1f,
                            float* __restrict__ bias0, float* __restrict__ bias1,
                            int* __restrict__ prog)
{
  int stride = gridDim.x * blockDim.x;
  int idx0 = blockIdx.x * blockDim.x + threadIdx.x;
  const int N0 = 6*32*64*8;      // layer0: K=192 (x 64 | h 128)
  const int N1 = 8*32*64*8;      // layer1: K=256 (h1 128 | h 128)
  for (int e = idx0; e < N0 + N1 + 1024 + 128; e += stride) {
    if (e < N0) {
      int j = e & 7; int le = e >> 3; int lane = le & 63; int frag = le >> 6;
      int kt = frag >> 5, ntile = frag & 31;
      int n = ntile*16 + (lane & 15);
      int kk = kt*32 + ((lane >> 4) << 3) + j;
      float v = (kk < 64) ? wih0[n*64 + kk] : whh0[n*128 + (kk - 64)];
      w0f[e] = (_Float16)v;
    } else if (e < N0 + N1) {
      int e2 = e - N0;
      int j = e2 & 7; int le = e2 >> 3; int lane = le & 63; int frag = le >> 6;
      int kt = frag >> 5, ntile = frag & 31;
      int n = ntile*16 + (lane & 15);
      int kk = kt*32 + ((lane >> 4) << 3) + j;
      float v = (kk < 128) ? wih1[n*128 + kk] : whh1[n*128 + (kk - 128)];
      w1f[e2] = (_Float16)v;
    } else if (e < N0 + N1 + 1024) {
      int i = e - (N0 + N1);
      if (i < 512) bias0[i] = bih0[i] + bhh0[i];
      else         bias1[i - 512] = bih1[i - 512] + bhh1[i - 512];
    } else {
      prog[e - (N0 + N1 + 1024)] = 0;    // per-row-block progress flags
    }
  }
}

// ---------------- fused pipelined 2-layer LSTM ----------------
// Grid 256, block 512 (8 waves). Blocks 0..127: layer 0, rows 4b..4b+3.
// Blocks 128..255: layer 1, same rows, lagged ~3 windows behind l0 via prog[].
// 1 block/CU forced by regs (AGPR 96-128 + VGPR ~120) and LDS (84-92KB) ->
// all 256 blocks co-resident -> flag spin-wait is deadlock-free.
// 4 rows ride M-rows {0,4,8,12} of the same 16x16 MFMA tile: per wave still
// 16 recurrent MFMAs/step; epilogue uses all 64 lanes (1 unit/lane).
// Handoff: l0 flushes window W (8 steps) to h1 at window W+1 phase 0; after
// the phase-1 __syncthreads (vmcnt drained) tid0 does __threadfence (L2
// writeback) + release-store prog=W+1. l1 acquire-polls prog >= B+3 before
// issuing its stage load of superwindow B+2 (buffer_inv on acquire).
__global__ __launch_bounds__(512, 2) void lstm_fused(const float* __restrict__ x,
    const _Float16* __restrict__ w0f, const float* __restrict__ bias0,
    const _Float16* __restrict__ w1f, const float* __restrict__ bias1,
    const float* __restrict__ wlin, const float* __restrict__ blin,
    _Float16* __restrict__ h1, int* __restrict__ prog,
    float* __restrict__ out)
{
  __shared__ __align__(16) char smem[92160];
  const int tid = threadIdx.x;
  const int lane = tid & 63;
  const int w = tid >> 6;
  const int role = blockIdx.x >> 7;
  const int rblk = blockIdx.x & 127;
  const int r0 = rblk * 4;
  int* pr = prog + rblk;

  const int li = lane & 15;
  const int en = w*16 + li;                 // column 0..127
  const int rbi = lane >> 4;                // block-row 0..3
  const bool arow = (lane & 3) == 0;        // A-frag carrier lanes (m=4*msl)
  const int aidx = ((lane >> 2) & 3)*4 + (lane >> 4);   // msl*4 + kgrp
  const int eoff = ((en>>5)*16 + rbi*4 + ((en&31)>>3))*8 + (en&7);

  // staging thread map (both roles): sdt = step-in-SW 0..7, srow = row 0..3
  const int sdt = tid >> 6, srow = (tid >> 4) & 3;
  const int sm = (sdt & 3)*4 + srow;        // A-frag m = dt*4 + row

  if (role == 0) {
    // ================= layer 0 =================
    float* preLDS   = (float*)smem;                   // [2][16m][128en][4g] = 64KB
    _Float16* aFh   = (_Float16*)(smem + 65536);      // [2 SW][4 fs][64][8] = 8KB
    half8* aF       = (half8*)aFh;
    half8* hA       = (half8*)(smem + 73728);         // [2][64] = 2KB
    _Float16* hist  = (_Float16*)(smem + 75776);      // [16][4][128] = 16KB

    ((int*)hA)[tid] = 0;

    half8 bf[6][4];                                   // 24 frags = 96 AGPR
#pragma unroll
    for (int kt = 0; kt < 6; ++kt)
#pragma unroll
      for (int g = 0; g < 4; ++g) {
        bf[kt][g] = *reinterpret_cast<const half8*>(w0f + (size_t)((kt*32 + g*8 + w)*64 + lane)*8);
        asm volatile("" : "+a"(bf[kt][g]));
      }
    float bias_v[4];
#pragma unroll
    for (int g = 0; g < 4; ++g) bias_v[g] = bias0[g*128 + en];

    const int scq = (tid & 15) * 4;                   // x col quad
    const int sfs = (sdt >> 2)*2 + (scq >> 5);        // fragset = pb*2 + kt
    const int sidx = (sfs*64 + ((((scq&31)>>3)<<4) | sm))*8 + (scq & 7);
    const int fr = tid >> 7, fdt = (tid >> 4) & 7, fn = (tid & 15)*8;

    // prologue: stage SW0, SW1
    {
      float4 v0 = *reinterpret_cast<const float4*>(x + ((size_t)(r0+srow)*512 + sdt)*64 + scq);
      float4 v1 = *reinterpret_cast<const float4*>(x + ((size_t)(r0+srow)*512 + 8 + sdt)*64 + scq);
      half4 h0 = {(_Float16)v0.x, (_Float16)v0.y, (_Float16)v0.z, (_Float16)v0.w};
      half4 h1v = {(_Float16)v1.x, (_Float16)v1.y, (_Float16)v1.z, (_Float16)v1.w};
      *reinterpret_cast<half4*>(aFh + sidx) = h0;
      *reinterpret_cast<half4*>(aFh + 2048 + sidx) = h1v;
    }
    __syncthreads();

    auto proj = [&](auto swb_t, auto pbl_t, auto slot_t) {
      constexpr int SWB = decltype(swb_t)::value;
      constexpr int PBL = decltype(pbl_t)::value;
      constexpr int SLOT = decltype(slot_t)::value;
      floatx4 accP[4];
#pragma unroll
      for (int g = 0; g < 4; ++g) { float bb = bias_v[g]; accP[g] = (floatx4){bb,bb,bb,bb}; }
#pragma unroll
      for (int kt = 0; kt < 2; ++kt) {
        half8 af = aF[SWB*256 + (PBL*2 + kt)*64 + lane];
#pragma unroll
        for (int g = 0; g < 4; ++g)
          accP[g] = __builtin_amdgcn_mfma_f32_16x16x32_f16(af, bf[kt][g], accP[g], 0, 0, 0);
      }
#pragma unroll
      for (int reg = 0; reg < 4; ++reg) {
        int m = (lane>>4)*4 + reg;
        floatx4 pv = (floatx4){accP[0][reg], accP[1][reg], accP[2][reg], accP[3][reg]};
        *reinterpret_cast<floatx4*>(&preLDS[SLOT*8192 + (m*128 + en)*4]) = pv;
      }
    };

    proj(ic<0>{}, ic<0>{}, ic<0>{});       // 4-batch 0 -> slot0

    half8 a0 = {}, a1 = {}, a2 = {}, a3 = {};
    float4 sv;
    float cst = 0.f;
    floatx4 acc[4];
#pragma unroll
    for (int g = 0; g < 4; ++g) acc[g] = (floatx4){0.f,0.f,0.f,0.f};
    floatx4 p4c = *reinterpret_cast<const floatx4*>(&preLDS[(rbi*128 + en)*4]);

    auto core = [&](auto tag) {
      constexpr int TM = decltype(tag)::value;        // 0..15 (window-pair step)
      constexpr int CUR = TM & 1;
      constexpr int SLN = ((TM + 1) >> 2) & 1;
      constexpr int DTN = (TM + 1) & 3;
      if (arow) {
        a0 = hA[CUR*64 +  0 + aidx];
        a1 = hA[CUR*64 + 16 + aidx];
        a2 = hA[CUR*64 + 32 + aidx];
        a3 = hA[CUR*64 + 48 + aidx];
      }
      acc[0][0] = p4c[0]; acc[1][0] = p4c[1]; acc[2][0] = p4c[2]; acc[3][0] = p4c[3];
#pragma unroll
      for (int g = 0; g < 4; ++g)
        acc[g] = __builtin_amdgcn_mfma_f32_16x16x32_f16(a0, bf[2][g], acc[g], 0, 0, 0);
#pragma unroll
      for (int g = 0; g < 4; ++g)
        acc[g] = __builtin_amdgcn_mfma_f32_16x16x32_f16(a1, bf[3][g], acc[g], 0, 0, 0);
#pragma unroll
      for (int g = 0; g < 4; ++g)
        acc[g] = __builtin_amdgcn_mfma_f32_16x16x32_f16(a2, bf[4][g], acc[g], 0, 0, 0);
#pragma unroll
      for (int g = 0; g < 4; ++g)
        acc[g] = __builtin_amdgcn_mfma_f32_16x16x32_f16(a3, bf[5][g], acc[g], 0, 0, 0);
      p4c = *reinterpret_cast<const floatx4*>(&preLDS[SLN*8192 + ((DTN*4 + rbi)*128 + en)*4]);
      float ii = fast_sigmoid(acc[0][0]);
      float ff = fast_sigmoid(acc[1][0]);
      float gg = fast_tanh(acc[2][0]);
      float oo = fast_sigmoid(acc[3][0]);
      cst = ff*cst + ii*gg;
      float hv2 = oo*fast_tanh(cst);
      _Float16 hh = (_Float16)hv2;
      ((_Float16*)hA)[(CUR^1)*512 + eoff] = hh;
      hist[TM*512 + rbi*128 + en] = hh;
    };

    auto window = [&](int B, auto wpar_t) {
      constexpr int WPAR = decltype(wpar_t)::value;
      __syncthreads();
      if (B >= 1) {                        // flush window B-1 (hist slots (WPAR^1)*8..)
        half8 v = *reinterpret_cast<const half8*>(&hist[((WPAR^1)*8 + fdt)*512 + fr*128 + fn]);
        *reinterpret_cast<half8*>(h1 + ((size_t)(r0+fr)*512 + (B-1)*8 + fdt)*128 + fn) = v;
      }
      proj(ic<WPAR>{}, ic<1>{}, ic<1>{});  // 4-batch 2B+1 -> slot1
      core(ic<WPAR*8 + 0>{});
      __syncthreads();
      if (tid == 0 && B >= 1) {            // windows <= B-1 flushed & drained
        __threadfence();
        __hip_atomic_store(pr, B, __ATOMIC_RELEASE, __HIP_MEMORY_SCOPE_AGENT);
      }
      if (B < 62)
        sv = *reinterpret_cast<const float4*>(x + ((size_t)(r0+srow)*512 + (B+2)*8 + sdt)*64 + scq);
      core(ic<WPAR*8 + 1>{});
      __syncthreads();
      core(ic<WPAR*8 + 2>{});
      __syncthreads();
      if (B < 62) {                        // write staged SW B+2 -> buf WPAR
        half4 hv = {(_Float16)sv.x, (_Float16)sv.y, (_Float16)sv.z, (_Float16)sv.w};
        *reinterpret_cast<half4*>(aFh + WPAR*2048 + sidx) = hv;
      }
      core(ic<WPAR*8 + 3>{});
      __syncthreads();
      if (B < 63) proj(ic<WPAR^1>{}, ic<0>{}, ic<0>{});  // 4-batch 2B+2 -> slot0
      core(ic<WPAR*8 + 4>{});
      __syncthreads(); core(ic<WPAR*8 + 5>{});
      __syncthreads(); core(ic<WPAR*8 + 6>{});
      __syncthreads(); core(ic<WPAR*8 + 7>{});
    };

    for (int bp = 0; bp < 32; ++bp) {
      window(2*bp,     ic<0>{});
      window(2*bp + 1, ic<1>{});
    }
    __syncthreads();
    {                                      // final flush: window 63 (slots 8..15)
      half8 v = *reinterpret_cast<const half8*>(&hist[(8 + fdt)*512 + fr*128 + fn]);
      *reinterpret_cast<half8*>(h1 + ((size_t)(r0+fr)*512 + 504 + fdt)*128 + fn) = v;
    }
    __syncthreads();                       // drain final flush
    if (tid == 0) {
      __threadfence();
      __hip_atomic_store(pr, 64, __ATOMIC_RELEASE, __HIP_MEMORY_SCOPE_AGENT);
    }
  } else {
    // ================= layer 1 (lagged consumer) =================
    float* preLDS   = (float*)smem;                   // 64KB
    _Float16* aFh   = (_Float16*)(smem + 65536);      // [2 SW][8 fs][64][8] = 16KB
    half8* aF       = (half8*)aFh;
    half8* hA       = (half8*)(smem + 81920);         // 2KB
    float* head     = (float*)(smem + 83968);         // 2KB

    ((int*)hA)[tid] = 0;

    half8 bf[8][4];                                   // 32 frags = 128 AGPR
#pragma unroll
    for (int kt = 0; kt < 8; ++kt)
#pragma unroll
      for (int g = 0; g < 4; ++g) {
        bf[kt][g] = *reinterpret_cast<const half8*>(w1f + (size_t)((kt*32 + g*8 + w)*64 + lane)*8);
        asm volatile("" : "+a"(bf[kt][g]));
      }
    float bias_v[4];
#pragma unroll
    for (int g = 0; g < 4; ++g) bias_v[g] = bias1[g*128 + en];

    const int sc8 = (tid & 15) * 8;                   // h1 col octet
    const int sfs = (sdt >> 2)*4 + (sc8 >> 5);        // fragset = pb*4 + kt
    const int sidx = (sfs*64 + ((((sc8&31)>>3)<<4) | sm))*8;
    const float wl = wlin[en];

    // prologue: wait for l0 windows 0,1; stage SW0, SW1
    while (__hip_atomic_load(pr, __ATOMIC_ACQUIRE, __HIP_MEMORY_SCOPE_AGENT) < 2)
      __builtin_amdgcn_s_sleep(8);
    {
      uint4 v0 = *reinterpret_cast<const uint4*>(h1 + ((size_t)(r0+srow)*512 + sdt)*128 + sc8);
      uint4 v1 = *reinterpret_cast<const uint4*>(h1 + ((size_t)(r0+srow)*512 + 8 + sdt)*128 + sc8);
      *reinterpret_cast<uint4*>(aFh + sidx) = v0;
      *reinterpret_cast<uint4*>(aFh + 4096 + sidx) = v1;
    }
    __syncthreads();

    auto proj = [&](auto swb_t, auto pbl_t, auto slot_t) {
      constexpr int SWB = decltype(swb_t)::value;
      constexpr int PBL = decltype(pbl_t)::value;
      constexpr int SLOT = decltype(slot_t)::value;
      floatx4 accP[4];
#pragma unroll
      for (int g = 0; g < 4; ++g) { float bb = bias_v[g]; accP[g] = (floatx4){bb,bb,bb,bb}; }
#pragma unroll
      for (int kt = 0; kt < 4; ++kt) {
        half8 af = aF[SWB*512 + (PBL*4 + kt)*64 + lane];
#pragma unroll
        for (int g = 0; g < 4; ++g)
          accP[g] = __builtin_amdgcn_mfma_f32_16x16x32_f16(af, bf[kt][g], accP[g], 0, 0, 0);
      }
#pragma unroll
      for (int reg = 0; reg < 4; ++reg) {
        int m = (lane>>4)*4 + reg;
        floatx4 pv = (floatx4){accP[0][reg], accP[1][reg], accP[2][reg], accP[3][reg]};
        *reinterpret_cast<floatx4*>(&preLDS[SLOT*8192 + (m*128 + en)*4]) = pv;
      }
    };

    proj(ic<0>{}, ic<0>{}, ic<0>{});       // 4-batch 0 -> slot0

    half8 a0 = {}, a1 = {}, a2 = {}, a3 = {};
    uint4 sv;
    float cst = 0.f, hl = 0.f;
    floatx4 acc[4];
#pragma unroll
    for (int g = 0; g < 4; ++g) acc[g] = (floatx4){0.f,0.f,0.f,0.f};
    floatx4 p4c = *reinterpret_cast<const floatx4*>(&preLDS[(rbi*128 + en)*4]);

    auto core = [&](auto tag) {
      constexpr int TM = decltype(tag)::value;
      constexpr int CUR = TM & 1;
      constexpr int SLN = ((TM + 1) >> 2) & 1;
      constexpr int DTN = (TM + 1) & 3;
      if (arow) {
        a0 = hA[CUR*64 +  0 + aidx];
        a1 = hA[CUR*64 + 16 + aidx];
        a2 = hA[CUR*64 + 32 + aidx];
        a3 = hA[CUR*64 + 48 + aidx];
      }
      acc[0][0] = p4c[0]; acc[1][0] = p4c[1]; acc[2][0] = p4c[2]; acc[3][0] = p4c[3];
#pragma unroll
      for (int g = 0; g < 4; ++g)
        acc[g] = __builtin_amdgcn_mfma_f32_16x16x32_f16(a0, bf[4][g], acc[g], 0, 0, 0);
#pragma unroll
      for (int g = 0; g < 4; ++g)
        acc[g] = __builtin_amdgcn_mfma_f32_16x16x32_f16(a1, bf[5][g], acc[g], 0, 0, 0);
#pragma unroll
      for (int g = 0; g < 4; ++g)
        acc[g] = __builtin_amdgcn_mfma_f32_16x16x32_f16(a2, bf[6][g], acc[g], 0, 0, 0);
#pragma unroll
      for (int g = 0; g < 4; ++g)
        acc[g] = __builtin_amdgcn_mfma_f32_16x16x32_f16(a3, bf[7][g], acc[g], 0, 0, 0);
      p4c = *reinterpret_cast<const floatx4*>(&preLDS[SLN*8192 + ((DTN*4 + rbi)*128 + en)*4]);
      float ii = fast_sigmoid(acc[0][0]);
      float ff = fast_sigmoid(acc[1][0]);
      float gg = fast_tanh(acc[2][0]);
      float oo = fast_sigmoid(acc[3][0]);
      cst = ff*cst + ii*gg;
      hl = oo*fast_tanh(cst);
      ((_Float16*)hA)[(CUR^1)*512 + eoff] = (_Float16)hl;
    };

    auto window = [&](int B, auto wpar_t) {
      constexpr int WPAR = decltype(wpar_t)::value;
      __syncthreads();
      proj(ic<WPAR>{}, ic<1>{}, ic<1>{});  // 4-batch 2B+1 -> slot1
      core(ic<WPAR*8 + 0>{});
      __syncthreads();
      if (B < 62) {                        // gate on producer, then stage SW B+2
        while (__hip_atomic_load(pr, __ATOMIC_ACQUIRE, __HIP_MEMORY_SCOPE_AGENT) < B + 3)
          __builtin_amdgcn_s_sleep(2);
        sv = *reinterpret_cast<const uint4*>(h1 + ((size_t)(r0+srow)*512 + (B+2)*8 + sdt)*128 + sc8);
      }
      core(ic<WPAR*8 + 1>{});
      __syncthreads();
      core(ic<WPAR*8 + 2>{});
      __syncthreads();
      if (B < 62)
        *reinterpret_cast<uint4*>(aFh + WPAR*4096 + sidx) = sv;
      core(ic<WPAR*8 + 3>{});
      __syncthreads();
      if (B < 63) proj(ic<WPAR^1>{}, ic<0>{}, ic<0>{});  // 4-batch 2B+2 -> slot0
      core(ic<WPAR*8 + 4>{});
      __syncthreads(); core(ic<WPAR*8 + 5>{});
      __syncthreads(); core(ic<WPAR*8 + 6>{});
      __syncthreads(); core(ic<WPAR*8 + 7>{});
    };

    for (int bp = 0; bp < 32; ++bp) {
      window(2*bp,     ic<0>{});
      window(2*bp + 1, ic<1>{});
    }

    // fused head: out[r0+rbi] = sum_en h_last * wlin + blin
    __syncthreads();
    head[rbi*128 + en] = hl * wl;
    __syncthreads();
    if (tid < 4) {
      float s = blin[0];
      for (int n = 0; n < 128; ++n) s += head[tid*128 + n];
      out[r0 + tid] = s;
    }
  }
}

extern "C" void kernel_launch(void* const* d_in, const int* in_sizes, int n_in,
                              void* d_out, int out_size, void* d_ws, size_t ws_size,
                              hipStream_t stream)
{
  const float* x    = (const float*)d_in[0];
  const float* wih0 = (const float*)d_in[1];
  const float* whh0 = (const float*)d_in[2];
  const float* bih0 = (const float*)d_in[3];
  const float* bhh0 = (const float*)d_in[4];
  const float* wih1 = (const float*)d_in[5];
  const float* whh1 = (const float*)d_in[6];
  const float* bih1 = (const float*)d_in[7];
  const float* bhh1 = (const float*)d_in[8];
  const float* wlin = (const float*)d_in[9];
  const float* blin = (const float*)d_in[10];
  float* out = (float*)d_out;

  char* ws = (char*)d_ws;
  _Float16* w0f = (_Float16*)(ws);               // 196608 B
  _Float16* w1f = (_Float16*)(ws + 196608);      // 262144 B
  float* bias0  = (float*)(ws + 458752);         // 2048 B
  float* bias1  = (float*)(ws + 460800);         // 2048 B
  int* prog     = (int*)(ws + 524288);           // 512 B progress flags
  _Float16* h1  = (_Float16*)(ws + 1048576);     // 64 MB inter-layer buffer

  prep_kernel<<<256, 256, 0, stream>>>(wih0, whh0, bih0, bhh0, wih1, whh1, bih1, bhh1,
                                       w0f, w1f, bias0, bias1, prog);
  lstm_fused<<<256, 512, 0, stream>>>(x, w0f, bias0, w1f, bias1, wlin, blin, h1, prog, out);
}